// Round 4
// baseline (311.781 us; speedup 1.0000x reference)
//
#include <hip/hip_runtime.h>
#include <hip/hip_bf16.h>

// GraphSAGE 2-layer forward. N=100000, E=1250000, 64 -> 64 -> 32, fp32.
//
// Round-17: p1/p2 (bucket + per-bucket CSR) replaced by direct counting-sort
// CSR. Rationale: with <=2048 blocks everything is resident at t=0, so a
// dispatch lasts as long as its slowest block; the bucket scatter->restage->
// rescatter path was the straggler, pinned at ~50us across 4 structural
// variants. New pipeline (deg/cursor direct, no bucket intermediate):
//   memset(deg=0)
//   pack+hist  : blocks 0-3 pack w1p/w2p; rest: deg[dst]++ (no-return atomics)
//   scan1      : per-1024-node block sums of deg
//   scan3      : inline-offset exclusive scan -> row_start + cursor copy
//   dense1+scatter : blocks 0..dblocks-1: bufA(xs)=x@Ws1+b1, t1n=bf16(x@Wn1)
//                    rest: p=atomicAdd(cursor[dst]); csr_src[p]=src (4 chains)
//   agg64_d2   : h1 = relu(xs + mean t1n[src]); d_out=h1@Ws2+b2, t2n=bf16(h1@Wn2)
//   agg32      : d_out += mean t2n[src]  (in place)
// agg64_d2 / agg32 byte-identical to round-15 (clean A/B on the CSR build).

#define NF 64
#define H1S 68            // h1s row stride in floats

typedef __attribute__((ext_vector_type(8))) short short8;
typedef __attribute__((ext_vector_type(8))) unsigned short ushort8v;
typedef __attribute__((ext_vector_type(4))) float floatx4;
typedef __attribute__((ext_vector_type(4))) int intx4;

__device__ __forceinline__ short bf16hi(float v) {
    __hip_bfloat16 h = __float2bfloat16(v);
    return *(short*)&h;
}
__device__ __forceinline__ float bf2f(short s) {
    __hip_bfloat16 h = *(__hip_bfloat16*)&s;
    return __bfloat162float(h);
}
__device__ __forceinline__ float bits2f(unsigned short u) {
    unsigned int x = ((unsigned int)u) << 16;
    union { unsigned int i; float f; } c; c.i = x; return c.f;
}

// ---------------- pack w1p/w2p + histogram deg ----------------
// w1p: [n*64+k] hi, [+8192] lo; n = dense1 out col (0-63 self, 64-127 neigh).
// w2p: [n*64+k] hi, [+4096] lo; n = dense2 out col (0-31 self, 32-63 neigh).
// Blocks 0-3: pack. Blocks 4..: histogram chunk of 1024 edges.

__global__ __launch_bounds__(256) void pack_hist_kernel(
        const int* __restrict__ dst, int* __restrict__ deg, int E, int N,
        const float* __restrict__ Ws1, const float* __restrict__ Wn1,
        const float* __restrict__ Ws2, const float* __restrict__ Wn2,
        unsigned short* __restrict__ w1p, unsigned short* __restrict__ w2p) {
    const int tid = threadIdx.x;
    if (blockIdx.x < 4) {
        const int part = blockIdx.x;                 // 0..3
        for (int i = tid; i < 32 * 64; i += 256) {   // w1: 32 cols per part
            int n = part * 32 + (i >> 6), k = i & 63;
            float v = (n < 64) ? Ws1[k * 64 + n] : Wn1[k * 64 + (n - 64)];
            short hv = bf16hi(v);
            w1p[n * 64 + k] = (unsigned short)hv;
            w1p[8192 + n * 64 + k] = (unsigned short)bf16hi(v - bf2f(hv));
        }
        for (int i = tid; i < 16 * 64; i += 256) {   // w2: 16 cols per part
            int n = part * 16 + (i >> 6), k = i & 63;
            float v = (n < 32) ? Ws2[k * 32 + n] : Wn2[k * 32 + (n - 32)];
            short hv = bf16hi(v);
            w2p[n * 64 + k] = (unsigned short)hv;
            w2p[4096 + n * 64 + k] = (unsigned short)bf16hi(v - bf2f(hv));
        }
        return;
    }
    const int base = (blockIdx.x - 4) * 1024 + tid;
    #pragma unroll
    for (int k = 0; k < 4; ++k) {
        int e = base + k * 256;
        if (e < E) {
            int d = dst[e];
            if ((unsigned)d < (unsigned)N) atomicAdd(&deg[d], 1);
        }
    }
}

// ---------------- scan1: per-block (1024 nodes) degree sums ----------------

__global__ __launch_bounds__(256) void scan1_kernel(const int* __restrict__ deg,
                                                    int* __restrict__ blocksum, int N) {
    __shared__ int red[256];
    const int t = threadIdx.x;
    const int base = blockIdx.x * 1024;
    int s = 0;
    #pragma unroll
    for (int k = 0; k < 4; ++k) {
        int n = base + t + k * 256;
        if (n < N) s += deg[n];
    }
    red[t] = s;
    __syncthreads();
    for (int off = 128; off > 0; off >>= 1) {
        if (t < off) red[t] += red[t + off];
        __syncthreads();
    }
    if (t == 0) blocksum[blockIdx.x] = red[0];
}

// ---------------- scan3: exclusive scan -> row_start + cursor ----------------
// Per-block offset computed inline (reduce of blocksum[0..b), p2-proven).

__global__ __launch_bounds__(256) void scan3_kernel(const int* __restrict__ deg,
                                                    const int* __restrict__ blocksum,
                                                    int* __restrict__ row_start,
                                                    int* __restrict__ cursor,
                                                    int N, int NB, int E) {
    __shared__ int lds[256];
    const int b = blockIdx.x, t = threadIdx.x;
    int partial = 0;
    for (int i = t; i < b; i += 256) partial += blocksum[i];
    lds[t] = partial;
    __syncthreads();
    for (int off = 128; off > 0; off >>= 1) {
        if (t < off) lds[t] += lds[t + off];
        __syncthreads();
    }
    const int boff = lds[0];
    __syncthreads();

    const int n0 = b * 1024 + t * 4;                 // 4 contiguous nodes
    int d0 = 0, d1 = 0, d2 = 0, d3 = 0;
    if (n0 + 3 < N) {
        intx4 v = *(const intx4*)(deg + n0);
        d0 = v[0]; d1 = v[1]; d2 = v[2]; d3 = v[3];
    } else {
        if (n0 + 0 < N) d0 = deg[n0];
        if (n0 + 1 < N) d1 = deg[n0 + 1];
        if (n0 + 2 < N) d2 = deg[n0 + 2];
        if (n0 + 3 < N) d3 = deg[n0 + 3];
    }
    const int tsum = d0 + d1 + d2 + d3;
    lds[t] = tsum;
    __syncthreads();
    for (int off = 1; off < 256; off <<= 1) {        // inclusive Hillis-Steele
        int v = (t >= off) ? lds[t - off] : 0;
        __syncthreads();
        lds[t] += v;
        __syncthreads();
    }
    const int excl = boff + lds[t] - tsum;
    const int r0 = excl, r1 = r0 + d0, r2 = r1 + d1, r3 = r2 + d2;
    if (n0 + 3 < N) {
        intx4 rv; rv[0] = r0; rv[1] = r1; rv[2] = r2; rv[3] = r3;
        *(intx4*)(row_start + n0) = rv;
        *(intx4*)(cursor + n0) = rv;
    } else {
        if (n0 + 0 < N) { row_start[n0]     = r0; cursor[n0]     = r0; }
        if (n0 + 1 < N) { row_start[n0 + 1] = r1; cursor[n0 + 1] = r1; }
        if (n0 + 2 < N) { row_start[n0 + 2] = r2; cursor[n0 + 2] = r2; }
        if (n0 + 3 < N) { row_start[n0 + 3] = r3; cursor[n0 + 3] = r3; }
    }
    if (b == NB - 1 && t == 255) row_start[N] = E;
}

// ---------------- fused dense1 (MFMA) + scatter ----------------
// Blocks [0, dblocks): dense1 (B frags from w1p global, no LDS).
// Blocks [dblocks, ...): scatter 1024 edges, 4 independent atomic chains.

__global__ __launch_bounds__(256) void dense1_scatter_kernel(
        const int* __restrict__ src, const int* __restrict__ dst,
        int* __restrict__ cursor, int* __restrict__ csr_src,
        int E, int dblocks,
        const float* __restrict__ X,                 // [N][64]
        const unsigned short* __restrict__ w1p,      // packed hi/lo fragments
        const float* __restrict__ bias,              // [64]
        float* __restrict__ outA,                    // [N][64] f32 (xs)
        unsigned short* __restrict__ outB,           // [N][64] bf16 bits (t1n)
        int N) {
    const int tid = threadIdx.x;

    if ((int)blockIdx.x >= dblocks) {
        // ---------------- scatter: csr_src[cursor[dst]++] = src ----------
        const int base = (blockIdx.x - dblocks) * 1024 + tid;
        const int e0 = base, e1 = base + 256, e2 = base + 512, e3 = base + 768;
        int d0 = 0, d1 = 0, d2 = 0, d3 = 0, s0 = 0, s1 = 0, s2 = 0, s3 = 0;
        const bool v0 = e0 < E, v1 = e1 < E, v2 = e2 < E, v3 = e3 < E;
        if (v0) { d0 = dst[e0]; s0 = src[e0]; }
        if (v1) { d1 = dst[e1]; s1 = src[e1]; }
        if (v2) { d2 = dst[e2]; s2 = src[e2]; }
        if (v3) { d3 = dst[e3]; s3 = src[e3]; }
        int p0 = 0, p1 = 0, p2 = 0, p3 = 0;
        if (v0 && (unsigned)d0 < (unsigned)N) p0 = atomicAdd(&cursor[d0], 1); else p0 = -1;
        if (v1 && (unsigned)d1 < (unsigned)N) p1 = atomicAdd(&cursor[d1], 1); else p1 = -1;
        if (v2 && (unsigned)d2 < (unsigned)N) p2 = atomicAdd(&cursor[d2], 1); else p2 = -1;
        if (v3 && (unsigned)d3 < (unsigned)N) p3 = atomicAdd(&cursor[d3], 1); else p3 = -1;
        if (p0 >= 0) csr_src[p0] = s0;
        if (p1 >= 0) csr_src[p1] = s1;
        if (p2 >= 0) csr_src[p2] = s2;
        if (p3 >= 0) csr_src[p3] = s3;
        return;
    }

    // ---------------- dense1: [N][64] @ [64][128] MFMA split-bf16 ----------
    // A: A[m=lane&15][k=(lane>>4)*8+j]; C/D: col=lane&15, row=(lane>>4)*4+reg.
    constexpr int NT = 8, NSELF = 4;
    const int lane = tid & 63;
    const int wid  = tid >> 6;
    const int m = lane & 15, quad = lane >> 4;
    const int rowblk = blockIdx.x * 128 + wid * 32;

    floatx4 acc[2][NT];
    #pragma unroll
    for (int rt = 0; rt < 2; ++rt)
        #pragma unroll
        for (int t = 0; t < NT; ++t) acc[rt][t] = (floatx4)(0.f);

    short8 ah[2][2], al[2][2];   // [rowset][k-half]
    #pragma unroll
    for (int rt = 0; rt < 2; ++rt) {
        int r = rowblk + rt * 16 + m;
        if (r >= N) r = N - 1;                       // clamped load, store guarded
        const float* xp = X + (size_t)r * 64 + quad * 8;
        #pragma unroll
        for (int h = 0; h < 2; ++h) {
            floatx4 f0 = *(const floatx4*)(xp + h * 32);
            floatx4 f1 = *(const floatx4*)(xp + h * 32 + 4);
            short8 hi, lo;
            #pragma unroll
            for (int j = 0; j < 4; ++j) {
                short hv = bf16hi(f0[j]);
                hi[j] = hv; lo[j] = bf16hi(f0[j] - bf2f(hv));
                short hv2 = bf16hi(f1[j]);
                hi[4 + j] = hv2; lo[4 + j] = bf16hi(f1[j] - bf2f(hv2));
            }
            ah[rt][h] = hi; al[rt][h] = lo;
        }
    }

    #pragma unroll
    for (int t = 0; t < NT; ++t) {
        int n = t * 16 + m;
        const unsigned short* ph = w1p + n * 64 + quad * 8;
        const unsigned short* pl = ph + 8192;
        #pragma unroll
        for (int h = 0; h < 2; ++h) {
            short8 bh = *(const short8*)(ph + h * 32);
            short8 bl = *(const short8*)(pl + h * 32);
            #pragma unroll
            for (int rt = 0; rt < 2; ++rt) {
                acc[rt][t] = __builtin_amdgcn_mfma_f32_16x16x32_bf16(ah[rt][h], bh, acc[rt][t], 0, 0, 0);
                acc[rt][t] = __builtin_amdgcn_mfma_f32_16x16x32_bf16(al[rt][h], bh, acc[rt][t], 0, 0, 0);
                acc[rt][t] = __builtin_amdgcn_mfma_f32_16x16x32_bf16(ah[rt][h], bl, acc[rt][t], 0, 0, 0);
            }
        }
    }

    #pragma unroll
    for (int rt = 0; rt < 2; ++rt) {
        #pragma unroll
        for (int t = 0; t < NT; ++t) {
            #pragma unroll
            for (int r4 = 0; r4 < 4; ++r4) {
                int row = rowblk + rt * 16 + quad * 4 + r4;
                if (row < N) {
                    if (t < NSELF) {
                        int col = t * 16 + m;
                        outA[(size_t)row * 64 + col] = acc[rt][t][r4] + bias[col];
                    } else {
                        int col = (t - NSELF) * 16 + m;
                        outB[(size_t)row * 64 + col] = (unsigned short)bf16hi(acc[rt][t][r4]);
                    }
                }
            }
        }
    }
}

// ---------------- fused agg64 + dense2 (MFMA epilogue) ----------------
// Block = 16 nodes, 4 waves. Half-wave owns TWO nodes gathered in one
// interleaved loop: 4 concurrent csr->t1n chains (branchless clamped
// gathers, select-accumulate). xs + w2p loads issued post-loop to hide
// under reduce/h1s/barrier. Then each wave one 16x16 MFMA tile.

__global__ __launch_bounds__(256) void agg64_d2_kernel(
        const unsigned short* __restrict__ t1n,      // [N][64] bf16 bits
        const float* __restrict__ xs,                // [N][64] self+bias
        const int* __restrict__ row_start,
        const int* __restrict__ csr_src,
        const unsigned short* __restrict__ w2p,      // packed hi/lo fragments
        const float* __restrict__ b2,                // [32]
        float* __restrict__ outD,                    // [N][32] (d_out)
        unsigned short* __restrict__ t2n,            // [N][32] bf16 bits
        int N, int E) {
    __shared__ float h1s[16][H1S];                   // 4.25 KB, padded stride
    const int tid = threadIdx.x;
    const int lane = tid & 63;
    const int wid  = tid >> 6;
    const int half = lane >> 5;                      // node select within pair
    const int g = (lane >> 3) & 3;                   // 4 groups of 8 per node
    const int c = lane & 7;
    const int nbase = blockIdx.x * 16;

    const int ln0 = wid * 4 + half;                  // this half-wave's 2 nodes
    const int ln1 = ln0 + 2;
    const int n0 = nbase + ln0, n1 = nbase + ln1;
    int beg0 = 0, end0 = 0, beg1 = 0, end1 = 0;
    if (n0 < N) { beg0 = row_start[n0]; end0 = row_start[n0 + 1]; }
    if (n1 < N) { beg1 = row_start[n1]; end1 = row_start[n1 + 1]; }

    float a0[8] = {0.f, 0.f, 0.f, 0.f, 0.f, 0.f, 0.f, 0.f};
    float a1[8] = {0.f, 0.f, 0.f, 0.f, 0.f, 0.f, 0.f, 0.f};
    int j0 = beg0 + g, j1 = beg1 + g;
    const int Em1 = E - 1;
    while ((j0 < end0) || (j1 < end1)) {
        // 4 index loads (clamped: safe garbage, masked out of the sum)
        int s0 = csr_src[min(j0, Em1)];
        int s1 = csr_src[min(j0 + 4, Em1)];
        int s2 = csr_src[min(j1, Em1)];
        int s3 = csr_src[min(j1 + 4, Em1)];
        s0 = ((unsigned)s0 < (unsigned)N) ? s0 : 0;
        s1 = ((unsigned)s1 < (unsigned)N) ? s1 : 0;
        s2 = ((unsigned)s2 < (unsigned)N) ? s2 : 0;
        s3 = ((unsigned)s3 < (unsigned)N) ? s3 : 0;
        // 4 concurrent row gathers
        ushort8v u0 = *(const ushort8v*)(t1n + (size_t)s0 * 64 + c * 8);
        ushort8v u1 = *(const ushort8v*)(t1n + (size_t)s1 * 64 + c * 8);
        ushort8v u2 = *(const ushort8v*)(t1n + (size_t)s2 * 64 + c * 8);
        ushort8v u3 = *(const ushort8v*)(t1n + (size_t)s3 * 64 + c * 8);
        const bool c00 = j0 < end0, c01 = j0 + 4 < end0;
        const bool c10 = j1 < end1, c11 = j1 + 4 < end1;
        #pragma unroll
        for (int i = 0; i < 8; ++i) {
            a0[i] += (c00 ? bits2f(u0[i]) : 0.f) + (c01 ? bits2f(u1[i]) : 0.f);
            a1[i] += (c10 ? bits2f(u2[i]) : 0.f) + (c11 ? bits2f(u3[i]) : 0.f);
        }
        j0 += 8; j1 += 8;
    }

    // issue tail loads now; latency hides under reduce + h1s + barrier
    const int m = lane & 15, quad = lane >> 4;
    const int coln = wid * 16 + m;
    const unsigned short* pb = w2p + coln * 64 + quad * 8;
    short8 bhf0 = *(const short8*)(pb);
    short8 bhf1 = *(const short8*)(pb + 32);
    short8 blf0 = *(const short8*)(pb + 4096);
    short8 blf1 = *(const short8*)(pb + 4096 + 32);

    floatx4 x00 = (floatx4)(0.f), x01 = (floatx4)(0.f);
    floatx4 x10 = (floatx4)(0.f), x11 = (floatx4)(0.f);
    if (g == 0) {
        if (n0 < N) {
            const float* p = xs + (size_t)n0 * 64 + c * 8;
            x00 = *(const floatx4*)p; x01 = *(const floatx4*)(p + 4);
        }
        if (n1 < N) {
            const float* p = xs + (size_t)n1 * 64 + c * 8;
            x10 = *(const floatx4*)p; x11 = *(const floatx4*)(p + 4);
        }
    }

    #pragma unroll
    for (int i = 0; i < 8; ++i) {                    // reduce over 4 groups (in-half)
        float v = a0[i];
        v += __shfl_xor(v, 8);
        v += __shfl_xor(v, 16);
        a0[i] = v;
        float w = a1[i];
        w += __shfl_xor(w, 8);
        w += __shfl_xor(w, 16);
        a1[i] = w;
    }
    if (g == 0) {                                    // 8 lanes per half write rows
        floatx4 h0, h1v;
        if (n0 < N) {
            float invd = 1.0f / fmaxf((float)(end0 - beg0), 1.0f);
            #pragma unroll
            for (int i = 0; i < 4; ++i) {
                h0[i]  = fmaxf(x00[i] + a0[i] * invd, 0.f);
                h1v[i] = fmaxf(x01[i] + a0[4 + i] * invd, 0.f);
            }
        } else { h0 = (floatx4)(0.f); h1v = (floatx4)(0.f); }
        *(floatx4*)&h1s[ln0][c * 8]     = h0;
        *(floatx4*)&h1s[ln0][c * 8 + 4] = h1v;
        if (n1 < N) {
            float invd = 1.0f / fmaxf((float)(end1 - beg1), 1.0f);
            #pragma unroll
            for (int i = 0; i < 4; ++i) {
                h0[i]  = fmaxf(x10[i] + a1[i] * invd, 0.f);
                h1v[i] = fmaxf(x11[i] + a1[4 + i] * invd, 0.f);
            }
        } else { h0 = (floatx4)(0.f); h1v = (floatx4)(0.f); }
        *(floatx4*)&h1s[ln1][c * 8]     = h0;
        *(floatx4*)&h1s[ln1][c * 8 + 4] = h1v;
    }
    __syncthreads();                                 // h1 tile ready

    // dense2: wave wid -> output cols wid*16 .. wid*16+15
    short8 ah[2], al[2];                             // A = h1s, split hi/lo
    #pragma unroll
    for (int h = 0; h < 2; ++h) {
        const float* hp = &h1s[m][quad * 8 + h * 32];
        floatx4 f0 = *(const floatx4*)hp;
        floatx4 f1 = *(const floatx4*)(hp + 4);
        short8 hi, lo;
        #pragma unroll
        for (int j = 0; j < 4; ++j) {
            short hv = bf16hi(f0[j]);
            hi[j] = hv; lo[j] = bf16hi(f0[j] - bf2f(hv));
            short hv2 = bf16hi(f1[j]);
            hi[4 + j] = hv2; lo[4 + j] = bf16hi(f1[j] - bf2f(hv2));
        }
        ah[h] = hi; al[h] = lo;
    }
    floatx4 acc2 = (floatx4)(0.f);
    acc2 = __builtin_amdgcn_mfma_f32_16x16x32_bf16(ah[0], bhf0, acc2, 0, 0, 0);
    acc2 = __builtin_amdgcn_mfma_f32_16x16x32_bf16(al[0], bhf0, acc2, 0, 0, 0);
    acc2 = __builtin_amdgcn_mfma_f32_16x16x32_bf16(ah[0], blf0, acc2, 0, 0, 0);
    acc2 = __builtin_amdgcn_mfma_f32_16x16x32_bf16(ah[1], bhf1, acc2, 0, 0, 0);
    acc2 = __builtin_amdgcn_mfma_f32_16x16x32_bf16(al[1], bhf1, acc2, 0, 0, 0);
    acc2 = __builtin_amdgcn_mfma_f32_16x16x32_bf16(ah[1], blf1, acc2, 0, 0, 0);
    #pragma unroll
    for (int r4 = 0; r4 < 4; ++r4) {
        int node = nbase + quad * 4 + r4;
        if (node < N) {
            if (coln < 32) outD[(size_t)node * 32 + coln] = acc2[r4] + b2[coln];
            else t2n[(size_t)node * 32 + (coln - 32)] = (unsigned short)bf16hi(acc2[r4]);
        }
    }
}

// ---------------- agg32: d_out += mean t2n[src], in place ----------------

__global__ __launch_bounds__(256) void agg32_kernel(float* io,  // [N][32] (d_out)
                                                    const unsigned short* __restrict__ t2n,
                                                    const int* __restrict__ row_start,
                                                    const int* __restrict__ csr_src, int N) {
    int n = (blockIdx.x * blockDim.x + threadIdx.x) >> 6;
    if (n >= N) return;
    int lane = threadIdx.x & 63;
    int g = lane >> 2, c = lane & 3;                 // lane covers feats c*8..c*8+7
    int beg = row_start[n], end = row_start[n + 1];
    // hoist in-place read: overlaps the gather chain instead of trailing it
    floatx4 s0v = (floatx4)(0.f), s1v = (floatx4)(0.f);
    size_t o = (size_t)n * 32 + c * 8;
    if (g == 0) {
        s0v = *(const floatx4*)(io + o);
        s1v = *(const floatx4*)(io + o + 4);
    }
    float acc[8] = {0.f, 0.f, 0.f, 0.f, 0.f, 0.f, 0.f, 0.f};
    for (int j = beg + g; j < end; j += 32) {
        int j2 = j + 16;
        int s0 = csr_src[j];
        ushort8v u0 = *(const ushort8v*)(t2n + (size_t)s0 * 32 + c * 8);
        if (j2 < end) {
            int s1 = csr_src[j2];
            ushort8v u1 = *(const ushort8v*)(t2n + (size_t)s1 * 32 + c * 8);
            #pragma unroll
            for (int i = 0; i < 8; ++i) acc[i] += bits2f(u0[i]) + bits2f(u1[i]);
        } else {
            #pragma unroll
            for (int i = 0; i < 8; ++i) acc[i] += bits2f(u0[i]);
        }
    }
    #pragma unroll
    for (int i = 0; i < 8; ++i) {
        float v = acc[i];
        v += __shfl_xor(v, 4);
        v += __shfl_xor(v, 8);
        v += __shfl_xor(v, 16);
        v += __shfl_xor(v, 32);
        acc[i] = v;
    }
    if (g == 0) {
        float inv = 1.0f / fmaxf((float)(end - beg), 1.0f);
        floatx4 r0, r1;
        #pragma unroll
        for (int i = 0; i < 4; ++i) {
            r0[i] = s0v[i] + acc[i] * inv;
            r1[i] = s1v[i] + acc[4 + i] * inv;
        }
        *(floatx4*)(io + o) = r0;
        *(floatx4*)(io + o + 4) = r1;
    }
}

// ---------------- fallback (round-2 atomic path) ----------------

__global__ __launch_bounds__(256) void deg_kernel(const int* __restrict__ dst,
                                                  float* __restrict__ deg, int E) {
    int e = blockIdx.x * blockDim.x + threadIdx.x;
    if (e < E) atomicAdd(&deg[dst[e]], 1.0f);
}

__global__ __launch_bounds__(256) void agg_atomic_kernel(const float* __restrict__ feats,
                                                         const int* __restrict__ src,
                                                         const int* __restrict__ dst,
                                                         float* __restrict__ agg, int E) {
    int tid = blockIdx.x * blockDim.x + threadIdx.x;
    if (tid >= E * NF) return;
    int e = tid >> 6, f = tid & 63;
    atomicAdd(&agg[(size_t)dst[e] * NF + f], feats[(size_t)src[e] * NF + f]);
}

__global__ __launch_bounds__(256) void layer1_fb_kernel(const float* __restrict__ x,
                                                        const float* __restrict__ agg,
                                                        const float* __restrict__ deg,
                                                        const float* __restrict__ Wself,
                                                        const float* __restrict__ Wneigh,
                                                        const float* __restrict__ b,
                                                        float* __restrict__ h1, int N) {
    int tid = blockIdx.x * blockDim.x + threadIdx.x;
    if (tid >= N * NF) return;
    int n = tid >> 6, c = tid & 63;
    float inv = 1.0f / fmaxf(deg[n], 1.0f);
    const float* xrow = x + (size_t)n * NF;
    const float* arow = agg + (size_t)n * NF;
    float acc = b[c];
    #pragma unroll
    for (int k = 0; k < NF; ++k) {
        acc += xrow[k] * Wself[k * NF + c];
        acc += (arow[k] * inv) * Wneigh[k * NF + c];
    }
    h1[tid] = fmaxf(acc, 0.f);
}

__global__ __launch_bounds__(256) void layer2_fb_kernel(const float* __restrict__ h1,
                                                        const float* __restrict__ agg,
                                                        const float* __restrict__ deg,
                                                        const float* __restrict__ Wself,
                                                        const float* __restrict__ Wneigh,
                                                        const float* __restrict__ b,
                                                        float* __restrict__ out, int N) {
    int tid = blockIdx.x * blockDim.x + threadIdx.x;
    if (tid >= N * 32) return;
    int n = tid >> 5, c = tid & 31;
    float inv = 1.0f / fmaxf(deg[n], 1.0f);
    const float* hrow = h1 + (size_t)n * NF;
    const float* arow = agg + (size_t)n * NF;
    float acc = b[c];
    #pragma unroll
    for (int k = 0; k < NF; ++k) {
        acc += hrow[k] * Wself[k * 32 + c];
        acc += (arow[k] * inv) * Wneigh[k * 32 + c];
    }
    out[tid] = acc;
}

// ---------------- launch ----------------

extern "C" void kernel_launch(void* const* d_in, const int* in_sizes, int n_in,
                              void* d_out, int out_size, void* d_ws, size_t ws_size,
                              hipStream_t stream) {
    const float* x        = (const float*)d_in[0];
    const int*   src      = (const int*)d_in[1];
    const int*   dst      = (const int*)d_in[2];
    const float* W_self1  = (const float*)d_in[3];
    const float* W_neigh1 = (const float*)d_in[4];
    const float* b1       = (const float*)d_in[5];
    const float* W_self2  = (const float*)d_in[6];
    const float* W_neigh2 = (const float*)d_in[7];
    const float* b2       = (const float*)d_in[8];
    float* out = (float*)d_out;

    const int N = in_sizes[0] / NF;          // 100000
    const int E = in_sizes[1];               // 1250000
    const int NB = (N + 1023) / 1024;        // scan blocks (98)

    // ws layout; gather tables 128B-aligned (round-10 proven: unaligned t1n
    // rows straddle 2 cachelines -> +70% FETCH)
    uintptr_t p = (uintptr_t)d_ws;
    auto align_up = [](uintptr_t v, uintptr_t a) { return (v + a - 1) & ~(a - 1); };
    int* deg = (int*)p;            p += (size_t)N * 4;       p = align_up(p, 64);
    int* cursor = (int*)p;         p += (size_t)N * 4;       p = align_up(p, 64);
    int* row_start = (int*)p;      p += ((size_t)N + 8) * 4; p = align_up(p, 64);
    int* blocksum = (int*)p;       p += 1024;                p = align_up(p, 64);
    unsigned short* w2p = (unsigned short*)p; p += 8192 * 2;  // 16 KB
    unsigned short* w1p = (unsigned short*)p; p += 16384 * 2; // 32 KB
    int* csr_src = (int*)p;        p += (size_t)E * 4;       p = align_up(p, 128);
    float* bufA = (float*)p;       p += (size_t)N * 64 * 4;  // [N][64] f32 (xs)
    unsigned short* t1n = (unsigned short*)p; p += (size_t)N * 64 * 2;  // 128B rows
    unsigned short* t2n = (unsigned short*)p; p += (size_t)N * 32 * 2;  // 64B rows
    size_t need = (size_t)(p - (uintptr_t)d_ws);             // ~51.5 MB

    bool fast = ws_size >= need
             && NB <= 256                                    // scan2-inline capacity
             && N >= 4
             && out_size >= N * 32;

    if (fast) {
        const int hblocks = (E + 1023) / 1024;               // hist/scatter blocks
        const int dblocks = (N + 127) / 128;                 // dense1 blocks
        hipMemsetAsync(deg, 0, (size_t)N * sizeof(int), stream);
        pack_hist_kernel<<<4 + hblocks, 256, 0, stream>>>(
            dst, deg, E, N, W_self1, W_neigh1, W_self2, W_neigh2, w1p, w2p);
        scan1_kernel<<<NB, 256, 0, stream>>>(deg, blocksum, N);
        scan3_kernel<<<NB, 256, 0, stream>>>(deg, blocksum, row_start, cursor, N, NB, E);
        dense1_scatter_kernel<<<dblocks + hblocks, 256, 0, stream>>>(
            src, dst, cursor, csr_src, E, dblocks,
            x, w1p, b1, bufA, t1n, N);
        agg64_d2_kernel<<<(N + 15) / 16, 256, 0, stream>>>(
            t1n, bufA, row_start, csr_src, w2p, b2, out, t2n, N, E);
        agg32_kernel<<<(N * 64 + 255) / 256, 256, 0, stream>>>(out, t2n,
                                                               row_start, csr_src, N);
    } else {
        // fallback: atomic path (~51.6 MB)
        float* deg_f = (float*)d_ws;
        float* agg = deg_f + N;
        float* h1  = agg + (size_t)N * NF;
        hipMemsetAsync(deg_f, 0, (size_t)(N + (size_t)N * NF) * sizeof(float), stream);
        deg_kernel<<<(E + 255) / 256, 256, 0, stream>>>(dst, deg_f, E);
        int at = E * NF;
        agg_atomic_kernel<<<(at + 255) / 256, 256, 0, stream>>>(x, src, dst, agg, E);
        layer1_fb_kernel<<<(N * NF + 255) / 256, 256, 0, stream>>>(x, agg, deg_f, W_self1,
                                                                   W_neigh1, b1, h1, N);
        hipMemsetAsync(agg, 0, (size_t)N * NF * sizeof(float), stream);
        agg_atomic_kernel<<<(at + 255) / 256, 256, 0, stream>>>(h1, src, dst, agg, E);
        layer2_fb_kernel<<<(N * 32 + 255) / 256, 256, 0, stream>>>(h1, agg, deg_f, W_self2,
                                                                   W_neigh2, b2, out, N);
    }
}

// Round 5
// 203.588 us; speedup vs baseline: 1.5314x; 1.5314x over previous
//
#include <hip/hip_runtime.h>
#include <hip/hip_bf16.h>

// GraphSAGE 2-layer forward. N=100000, E=1250000, 64 -> 64 -> 32, fp32.
//
// Round-18: counting-sort CSR (round-17) was an RFO disaster (WRITE 51->123MB,
// scatter 90us) -> CSR build reverted to round-15 bucket+window form (best
// known, 213.8us). New in this round:
//   - agg32 rewritten: 16-lane group per node (4 edge-groups x ILP2), 4
//     nodes/wave -> 6250 blocks instead of 25000 (12 latency rounds -> 3).
//     Reconstruction of invisible time said agg32 was ~40-50us.
//   - agg64_d2 gather loop: next iteration's csr indices prefetched before
//     consuming current gathers (breaks index->gather serial chain).
//   prep      : gcursor=0, pack w1p (dense1) + w2p (dense2)
//   p1+dense1 : blocks 0..dblocks-1: bufA(xs)=x@Ws1+b1, t1n=bf16(x@Wn1);
//               blocks dblocks..: bucket edges by dst>>8
//   p2        : per-bucket base (inline prefix) + LDS count/scan -> row_start+csr
//   agg64_d2  : h1 = relu(xs + mean t1n[src]); d_out = h1@Ws2+b2, t2n=bf16(h1@Wn2)
//   agg32     : d_out += mean t2n[src]   (in place)

#define NF 64
#define BW 256            // bucket width (nodes); rel = dst & 255
#define BSH 8
#define MAXB 512          // max buckets (LDS arrays)
#define CAPMAX 8192       // max edges per bucket region (mean 3197)
#define P1_CHUNK 2048
#define H1S 68            // h1s row stride in floats

typedef __attribute__((ext_vector_type(8))) short short8;
typedef __attribute__((ext_vector_type(8))) unsigned short ushort8v;
typedef __attribute__((ext_vector_type(4))) float floatx4;

__device__ __forceinline__ short bf16hi(float v) {
    __hip_bfloat16 h = __float2bfloat16(v);
    return *(short*)&h;
}
__device__ __forceinline__ float bf2f(short s) {
    __hip_bfloat16 h = *(__hip_bfloat16*)&s;
    return __bfloat162float(h);
}
__device__ __forceinline__ float bits2f(unsigned short u) {
    unsigned int x = ((unsigned int)u) << 16;
    union { unsigned int i; float f; } c; c.i = x; return c.f;
}

// ---------------- prep: zero gcursor + pack w1p/w2p ----------------
// w1p: [n*64+k] hi, [+8192] lo; n = dense1 out col (0-63 self, 64-127 neigh).
// w2p: [n*64+k] hi, [+4096] lo; n = dense2 out col (0-31 self, 32-63 neigh).

__global__ __launch_bounds__(256) void prep_kernel(
        int* __restrict__ gcursor,
        const float* __restrict__ Ws1, const float* __restrict__ Wn1,
        const float* __restrict__ Ws2, const float* __restrict__ Wn2,
        unsigned short* __restrict__ w1p, unsigned short* __restrict__ w2p) {
    const int tid = threadIdx.x;
    if (blockIdx.x == 0) {
        for (int i = tid; i < MAXB; i += 256) gcursor[i] = 0;
        return;
    }
    const int part = blockIdx.x - 1;                 // 0..3
    for (int i = tid; i < 32 * 64; i += 256) {       // w1: 32 cols per part
        int n = part * 32 + (i >> 6), k = i & 63;
        float v = (n < 64) ? Ws1[k * 64 + n] : Wn1[k * 64 + (n - 64)];
        short hv = bf16hi(v);
        w1p[n * 64 + k] = (unsigned short)hv;
        w1p[8192 + n * 64 + k] = (unsigned short)bf16hi(v - bf2f(hv));
    }
    for (int i = tid; i < 16 * 64; i += 256) {       // w2: 16 cols per part
        int n = part * 16 + (i >> 6), k = i & 63;
        float v = (n < 32) ? Ws2[k * 32 + n] : Wn2[k * 32 + (n - 32)];
        short hv = bf16hi(v);
        w2p[n * 64 + k] = (unsigned short)hv;
        w2p[4096 + n * 64 + k] = (unsigned short)bf16hi(v - bf2f(hv));
    }
}

// ---------------- fused p1 (bucket) + dense1 (MFMA) ----------------
// Blocks [0, dblocks): dense1 (B frags from w1p global, no LDS).
// Blocks [dblocks, ...): p1 bucketing (4 KB LDS).

__global__ __launch_bounds__(256) void p1_dense1_kernel(
        // p1 args
        const int* __restrict__ src, const int* __restrict__ dst,
        int* __restrict__ gcursor, unsigned* __restrict__ bucket,
        int E, int nbuckets, int dblocks,
        // dense1 args
        const float* __restrict__ X,                 // [N][64]
        const unsigned short* __restrict__ w1p,      // packed hi/lo fragments
        const float* __restrict__ bias,              // [64]
        float* __restrict__ outA,                    // [N][64] f32 (xs)
        unsigned short* __restrict__ outB,           // [N][64] bf16 bits (t1n)
        int N) {
    __shared__ int smem_i[2 * MAXB];                 // 4 KB
    const int tid = threadIdx.x;

    if ((int)blockIdx.x >= dblocks) {
        // ---------------- p1: bucket the edge list ----------------
        int* cnt   = smem_i;                         // [MAXB]
        int* cbase = smem_i + MAXB;                  // [MAXB]
        const int bid = blockIdx.x - dblocks;
        const int beg = bid * P1_CHUNK;
        const int end = min(E, beg + P1_CHUNK);
        for (int i = tid; i < nbuckets; i += 256) cnt[i] = 0;
        __syncthreads();
        for (int e = beg + tid; e < end; e += 256)
            atomicAdd(&cnt[dst[e] >> BSH], 1);
        __syncthreads();
        for (int i = tid; i < nbuckets; i += 256) {
            int c = cnt[i];
            cbase[i] = c ? atomicAdd(&gcursor[i], c) : 0;
            cnt[i] = 0;                              // reuse as local cursor
        }
        __syncthreads();
        for (int e = beg + tid; e < end; e += 256) {
            int d = dst[e];
            int r = d >> BSH;
            int p = cbase[r] + atomicAdd(&cnt[r], 1);
            if (p < CAPMAX)                          // clamp: no OOB even if skewed
                bucket[(size_t)r * CAPMAX + p] = ((unsigned)src[e] << BSH) | (unsigned)(d & (BW - 1));
        }
        return;
    }

    // ---------------- dense1: [N][64] @ [64][128] MFMA split-bf16 ----------
    // A: A[m=lane&15][k=(lane>>4)*8+j]; C/D: col=lane&15, row=(lane>>4)*4+reg.
    constexpr int NT = 8, NSELF = 4;
    const int lane = tid & 63;
    const int wid  = tid >> 6;
    const int m = lane & 15, quad = lane >> 4;
    const int rowblk = blockIdx.x * 128 + wid * 32;

    floatx4 acc[2][NT];
    #pragma unroll
    for (int rt = 0; rt < 2; ++rt)
        #pragma unroll
        for (int t = 0; t < NT; ++t) acc[rt][t] = (floatx4)(0.f);

    short8 ah[2][2], al[2][2];   // [rowset][k-half]
    #pragma unroll
    for (int rt = 0; rt < 2; ++rt) {
        int r = rowblk + rt * 16 + m;
        if (r >= N) r = N - 1;                       // clamped load, store guarded
        const float* xp = X + (size_t)r * 64 + quad * 8;
        #pragma unroll
        for (int h = 0; h < 2; ++h) {
            floatx4 f0 = *(const floatx4*)(xp + h * 32);
            floatx4 f1 = *(const floatx4*)(xp + h * 32 + 4);
            short8 hi, lo;
            #pragma unroll
            for (int j = 0; j < 4; ++j) {
                short hv = bf16hi(f0[j]);
                hi[j] = hv; lo[j] = bf16hi(f0[j] - bf2f(hv));
                short hv2 = bf16hi(f1[j]);
                hi[4 + j] = hv2; lo[4 + j] = bf16hi(f1[j] - bf2f(hv2));
            }
            ah[rt][h] = hi; al[rt][h] = lo;
        }
    }

    #pragma unroll
    for (int t = 0; t < NT; ++t) {
        int n = t * 16 + m;
        const unsigned short* ph = w1p + n * 64 + quad * 8;
        const unsigned short* pl = ph + 8192;
        #pragma unroll
        for (int h = 0; h < 2; ++h) {
            short8 bh = *(const short8*)(ph + h * 32);
            short8 bl = *(const short8*)(pl + h * 32);
            #pragma unroll
            for (int rt = 0; rt < 2; ++rt) {
                acc[rt][t] = __builtin_amdgcn_mfma_f32_16x16x32_bf16(ah[rt][h], bh, acc[rt][t], 0, 0, 0);
                acc[rt][t] = __builtin_amdgcn_mfma_f32_16x16x32_bf16(al[rt][h], bh, acc[rt][t], 0, 0, 0);
                acc[rt][t] = __builtin_amdgcn_mfma_f32_16x16x32_bf16(ah[rt][h], bl, acc[rt][t], 0, 0, 0);
            }
        }
    }

    #pragma unroll
    for (int rt = 0; rt < 2; ++rt) {
        #pragma unroll
        for (int t = 0; t < NT; ++t) {
            #pragma unroll
            for (int r4 = 0; r4 < 4; ++r4) {
                int row = rowblk + rt * 16 + quad * 4 + r4;
                if (row < N) {
                    if (t < NSELF) {
                        int col = t * 16 + m;
                        outA[(size_t)row * 64 + col] = acc[rt][t][r4] + bias[col];
                    } else {
                        int col = (t - NSELF) * 16 + m;
                        outB[(size_t)row * 64 + col] = (unsigned short)bf16hi(acc[rt][t][r4]);
                    }
                }
            }
        }
    }
}

// ---------------- p2: per-bucket CSR (exclusive window) ----------------

__global__ __launch_bounds__(256) void p2_csr_kernel(const unsigned* __restrict__ bucket,
                                                     const int* __restrict__ gcursor,
                                                     int* __restrict__ row_start,
                                                     int* __restrict__ csr_src,
                                                     int N, int nbuckets) {
    __shared__ unsigned stage[CAPMAX];   // 32 KB
    __shared__ int cnt[BW];
    __shared__ int excl[BW];
    const int r = blockIdx.x;
    const int tid = threadIdx.x;

    // base = sum_{i<r} min(gcursor[i], CAPMAX)   (excl[] as scratch)
    int partial = 0;
    for (int i = tid; i < r; i += 256) partial += min(gcursor[i], CAPMAX);
    excl[tid] = partial;
    __syncthreads();
    for (int off = 128; off > 0; off >>= 1) {
        if (tid < off) excl[tid] += excl[tid + off];
        __syncthreads();
    }
    const int base = excl[0];
    const int sz = min(gcursor[r], CAPMAX);
    const unsigned* bsrc = bucket + (size_t)r * CAPMAX;
    __syncthreads();

    cnt[tid] = 0;
    __syncthreads();
    for (int i = tid; i < sz; i += 256) {
        unsigned v = bsrc[i];
        stage[i] = v;
        atomicAdd(&cnt[v & (BW - 1)], 1);
    }
    __syncthreads();
    // inclusive scan (Hillis-Steele, 1 elem/thread since BW == blockDim)
    excl[tid] = cnt[tid];
    __syncthreads();
    for (int off = 1; off < BW; off <<= 1) {
        int v0 = (tid >= off) ? excl[tid - off] : 0;
        __syncthreads();
        excl[tid] += v0;
        __syncthreads();
    }
    int node = r * BW + tid;
    if (node < N) row_start[node] = base + excl[tid] - cnt[tid];
    if (r == nbuckets - 1 && tid == 0) row_start[N] = base + sz;
    __syncthreads();
    cnt[tid] = excl[tid] - cnt[tid];             // exclusive cursors
    __syncthreads();
    for (int i = tid; i < sz; i += 256) {
        unsigned v = stage[i];
        int p = atomicAdd(&cnt[v & (BW - 1)], 1);
        csr_src[base + p] = (int)(v >> BSH);     // window owned by this block only
    }
}

// ---------------- fused agg64 + dense2 (MFMA epilogue) ----------------
// Block = 16 nodes, 4 waves. Half-wave owns TWO nodes gathered in one
// interleaved loop: 4 concurrent csr->t1n chains, with NEXT iteration's
// csr indices prefetched before the current gathers are consumed (breaks
// the index->gather serial chain). xs + w2p loads issued post-loop.

__global__ __launch_bounds__(256) void agg64_d2_kernel(
        const unsigned short* __restrict__ t1n,      // [N][64] bf16 bits
        const float* __restrict__ xs,                // [N][64] self+bias
        const int* __restrict__ row_start,
        const int* __restrict__ csr_src,
        const unsigned short* __restrict__ w2p,      // packed hi/lo fragments
        const float* __restrict__ b2,                // [32]
        float* __restrict__ outD,                    // [N][32] (d_out)
        unsigned short* __restrict__ t2n,            // [N][32] bf16 bits
        int N, int E) {
    __shared__ float h1s[16][H1S];                   // 4.25 KB, padded stride
    const int tid = threadIdx.x;
    const int lane = tid & 63;
    const int wid  = tid >> 6;
    const int half = lane >> 5;                      // node select within pair
    const int g = (lane >> 3) & 3;                   // 4 groups of 8 per node
    const int c = lane & 7;
    const int nbase = blockIdx.x * 16;

    const int ln0 = wid * 4 + half;                  // this half-wave's 2 nodes
    const int ln1 = ln0 + 2;
    const int n0 = nbase + ln0, n1 = nbase + ln1;
    int beg0 = 0, end0 = 0, beg1 = 0, end1 = 0;
    if (n0 < N) { beg0 = row_start[n0]; end0 = row_start[n0 + 1]; }
    if (n1 < N) { beg1 = row_start[n1]; end1 = row_start[n1 + 1]; }

    float a0[8] = {0.f, 0.f, 0.f, 0.f, 0.f, 0.f, 0.f, 0.f};
    float a1[8] = {0.f, 0.f, 0.f, 0.f, 0.f, 0.f, 0.f, 0.f};
    int j0 = beg0 + g, j1 = beg1 + g;
    const int Em1 = E - 1;
    // prefetched index set for the current iteration
    int i0 = csr_src[min(j0, Em1)];
    int i1 = csr_src[min(j0 + 4, Em1)];
    int i2 = csr_src[min(j1, Em1)];
    int i3 = csr_src[min(j1 + 4, Em1)];
    while ((j0 < end0) || (j1 < end1)) {
        int s0 = ((unsigned)i0 < (unsigned)N) ? i0 : 0;
        int s1 = ((unsigned)i1 < (unsigned)N) ? i1 : 0;
        int s2 = ((unsigned)i2 < (unsigned)N) ? i2 : 0;
        int s3 = ((unsigned)i3 < (unsigned)N) ? i3 : 0;
        // 4 concurrent row gathers
        ushort8v u0 = *(const ushort8v*)(t1n + (size_t)s0 * 64 + c * 8);
        ushort8v u1 = *(const ushort8v*)(t1n + (size_t)s1 * 64 + c * 8);
        ushort8v u2 = *(const ushort8v*)(t1n + (size_t)s2 * 64 + c * 8);
        ushort8v u3 = *(const ushort8v*)(t1n + (size_t)s3 * 64 + c * 8);
        // prefetch next iteration's indices (overlap gather latency)
        i0 = csr_src[min(j0 + 8, Em1)];
        i1 = csr_src[min(j0 + 12, Em1)];
        i2 = csr_src[min(j1 + 8, Em1)];
        i3 = csr_src[min(j1 + 12, Em1)];
        const bool c00 = j0 < end0, c01 = j0 + 4 < end0;
        const bool c10 = j1 < end1, c11 = j1 + 4 < end1;
        #pragma unroll
        for (int i = 0; i < 8; ++i) {
            a0[i] += (c00 ? bits2f(u0[i]) : 0.f) + (c01 ? bits2f(u1[i]) : 0.f);
            a1[i] += (c10 ? bits2f(u2[i]) : 0.f) + (c11 ? bits2f(u3[i]) : 0.f);
        }
        j0 += 8; j1 += 8;
    }

    // issue tail loads now; latency hides under reduce + h1s + barrier
    const int m = lane & 15, quad = lane >> 4;
    const int coln = wid * 16 + m;
    const unsigned short* pb = w2p + coln * 64 + quad * 8;
    short8 bhf0 = *(const short8*)(pb);
    short8 bhf1 = *(const short8*)(pb + 32);
    short8 blf0 = *(const short8*)(pb + 4096);
    short8 blf1 = *(const short8*)(pb + 4096 + 32);

    floatx4 x00 = (floatx4)(0.f), x01 = (floatx4)(0.f);
    floatx4 x10 = (floatx4)(0.f), x11 = (floatx4)(0.f);
    if (g == 0) {
        if (n0 < N) {
            const float* p = xs + (size_t)n0 * 64 + c * 8;
            x00 = *(const floatx4*)p; x01 = *(const floatx4*)(p + 4);
        }
        if (n1 < N) {
            const float* p = xs + (size_t)n1 * 64 + c * 8;
            x10 = *(const floatx4*)p; x11 = *(const floatx4*)(p + 4);
        }
    }

    #pragma unroll
    for (int i = 0; i < 8; ++i) {                    // reduce over 4 groups (in-half)
        float v = a0[i];
        v += __shfl_xor(v, 8);
        v += __shfl_xor(v, 16);
        a0[i] = v;
        float w = a1[i];
        w += __shfl_xor(w, 8);
        w += __shfl_xor(w, 16);
        a1[i] = w;
    }
    if (g == 0) {                                    // 8 lanes per half write rows
        floatx4 h0, h1v;
        if (n0 < N) {
            float invd = 1.0f / fmaxf((float)(end0 - beg0), 1.0f);
            #pragma unroll
            for (int i = 0; i < 4; ++i) {
                h0[i]  = fmaxf(x00[i] + a0[i] * invd, 0.f);
                h1v[i] = fmaxf(x01[i] + a0[4 + i] * invd, 0.f);
            }
        } else { h0 = (floatx4)(0.f); h1v = (floatx4)(0.f); }
        *(floatx4*)&h1s[ln0][c * 8]     = h0;
        *(floatx4*)&h1s[ln0][c * 8 + 4] = h1v;
        if (n1 < N) {
            float invd = 1.0f / fmaxf((float)(end1 - beg1), 1.0f);
            #pragma unroll
            for (int i = 0; i < 4; ++i) {
                h0[i]  = fmaxf(x10[i] + a1[i] * invd, 0.f);
                h1v[i] = fmaxf(x11[i] + a1[4 + i] * invd, 0.f);
            }
        } else { h0 = (floatx4)(0.f); h1v = (floatx4)(0.f); }
        *(floatx4*)&h1s[ln1][c * 8]     = h0;
        *(floatx4*)&h1s[ln1][c * 8 + 4] = h1v;
    }
    __syncthreads();                                 // h1 tile ready

    // dense2: wave wid -> output cols wid*16 .. wid*16+15
    short8 ah[2], al[2];                             // A = h1s, split hi/lo
    #pragma unroll
    for (int h = 0; h < 2; ++h) {
        const float* hp = &h1s[m][quad * 8 + h * 32];
        floatx4 f0 = *(const floatx4*)hp;
        floatx4 f1 = *(const floatx4*)(hp + 4);
        short8 hi, lo;
        #pragma unroll
        for (int j = 0; j < 4; ++j) {
            short hv = bf16hi(f0[j]);
            hi[j] = hv; lo[j] = bf16hi(f0[j] - bf2f(hv));
            short hv2 = bf16hi(f1[j]);
            hi[4 + j] = hv2; lo[4 + j] = bf16hi(f1[j] - bf2f(hv2));
        }
        ah[h] = hi; al[h] = lo;
    }
    floatx4 acc2 = (floatx4)(0.f);
    acc2 = __builtin_amdgcn_mfma_f32_16x16x32_bf16(ah[0], bhf0, acc2, 0, 0, 0);
    acc2 = __builtin_amdgcn_mfma_f32_16x16x32_bf16(al[0], bhf0, acc2, 0, 0, 0);
    acc2 = __builtin_amdgcn_mfma_f32_16x16x32_bf16(ah[0], blf0, acc2, 0, 0, 0);
    acc2 = __builtin_amdgcn_mfma_f32_16x16x32_bf16(ah[1], bhf1, acc2, 0, 0, 0);
    acc2 = __builtin_amdgcn_mfma_f32_16x16x32_bf16(al[1], bhf1, acc2, 0, 0, 0);
    acc2 = __builtin_amdgcn_mfma_f32_16x16x32_bf16(ah[1], blf1, acc2, 0, 0, 0);
    #pragma unroll
    for (int r4 = 0; r4 < 4; ++r4) {
        int node = nbase + quad * 4 + r4;
        if (node < N) {
            if (coln < 32) outD[(size_t)node * 32 + coln] = acc2[r4] + b2[coln];
            else t2n[(size_t)node * 32 + (coln - 32)] = (unsigned short)bf16hi(acc2[r4]);
        }
    }
}

// ---------------- agg32: d_out += mean t2n[src], in place ----------------
// 16-lane group per node (4 edge-groups x ILP2 = 8 gathers in flight),
// 4 nodes/wave, 16 nodes/block -> 6250 blocks (was 25000, 1 node/wave).

__global__ __launch_bounds__(256) void agg32_kernel(float* io,  // [N][32] (d_out)
                                                    const unsigned short* __restrict__ t2n,
                                                    const int* __restrict__ row_start,
                                                    const int* __restrict__ csr_src,
                                                    int N, int E) {
    const int tid = threadIdx.x;
    const int lane = tid & 63;
    const int wid = tid >> 6;
    const int slot = lane >> 4;                      // 4 nodes per wave
    const int g = (lane >> 2) & 3;                   // 4 edge-groups per node
    const int c = lane & 3;                          // 16B chunk of 64B row
    const int n = blockIdx.x * 16 + wid * 4 + slot;

    int beg = 0, end = 0;
    if (n < N) { beg = row_start[n]; end = row_start[n + 1]; }

    // hoist in-place read: overlaps the gather chain instead of trailing it
    floatx4 s0v = (floatx4)(0.f), s1v = (floatx4)(0.f);
    size_t o = (size_t)n * 32 + c * 8;
    if (n < N && g == 0) {
        s0v = *(const floatx4*)(io + o);
        s1v = *(const floatx4*)(io + o + 4);
    }

    float acc[8] = {0.f, 0.f, 0.f, 0.f, 0.f, 0.f, 0.f, 0.f};
    const int Em1 = E - 1;
    for (int j = beg + g; j < end; j += 8) {
        int j2 = j + 4;
        int s0 = csr_src[j];                         // j < end <= E guaranteed
        int s1 = csr_src[min(j2, Em1)];
        s0 = ((unsigned)s0 < (unsigned)N) ? s0 : 0;
        s1 = ((unsigned)s1 < (unsigned)N) ? s1 : 0;
        ushort8v u0 = *(const ushort8v*)(t2n + (size_t)s0 * 32 + c * 8);
        ushort8v u1 = *(const ushort8v*)(t2n + (size_t)s1 * 32 + c * 8);
        const bool c1 = j2 < end;
        #pragma unroll
        for (int i = 0; i < 8; ++i)
            acc[i] += bits2f(u0[i]) + (c1 ? bits2f(u1[i]) : 0.f);
    }
    #pragma unroll
    for (int i = 0; i < 8; ++i) {                    // reduce over 4 groups (16-lane)
        float v = acc[i];
        v += __shfl_xor(v, 4);
        v += __shfl_xor(v, 8);
        acc[i] = v;
    }
    if (n < N && g == 0) {
        float inv = 1.0f / fmaxf((float)(end - beg), 1.0f);
        floatx4 r0, r1;
        #pragma unroll
        for (int i = 0; i < 4; ++i) {
            r0[i] = s0v[i] + acc[i] * inv;
            r1[i] = s1v[i] + acc[4 + i] * inv;
        }
        *(floatx4*)(io + o) = r0;
        *(floatx4*)(io + o + 4) = r1;
    }
}

// ---------------- fallback (round-2 atomic path) ----------------

__global__ __launch_bounds__(256) void deg_kernel(const int* __restrict__ dst,
                                                  float* __restrict__ deg, int E) {
    int e = blockIdx.x * blockDim.x + threadIdx.x;
    if (e < E) atomicAdd(&deg[dst[e]], 1.0f);
}

__global__ __launch_bounds__(256) void agg_atomic_kernel(const float* __restrict__ feats,
                                                         const int* __restrict__ src,
                                                         const int* __restrict__ dst,
                                                         float* __restrict__ agg, int E) {
    int tid = blockIdx.x * blockDim.x + threadIdx.x;
    if (tid >= E * NF) return;
    int e = tid >> 6, f = tid & 63;
    atomicAdd(&agg[(size_t)dst[e] * NF + f], feats[(size_t)src[e] * NF + f]);
}

__global__ __launch_bounds__(256) void layer1_fb_kernel(const float* __restrict__ x,
                                                        const float* __restrict__ agg,
                                                        const float* __restrict__ deg,
                                                        const float* __restrict__ Wself,
                                                        const float* __restrict__ Wneigh,
                                                        const float* __restrict__ b,
                                                        float* __restrict__ h1, int N) {
    int tid = blockIdx.x * blockDim.x + threadIdx.x;
    if (tid >= N * NF) return;
    int n = tid >> 6, c = tid & 63;
    float inv = 1.0f / fmaxf(deg[n], 1.0f);
    const float* xrow = x + (size_t)n * NF;
    const float* arow = agg + (size_t)n * NF;
    float acc = b[c];
    #pragma unroll
    for (int k = 0; k < NF; ++k) {
        acc += xrow[k] * Wself[k * NF + c];
        acc += (arow[k] * inv) * Wneigh[k * NF + c];
    }
    h1[tid] = fmaxf(acc, 0.f);
}

__global__ __launch_bounds__(256) void layer2_fb_kernel(const float* __restrict__ h1,
                                                        const float* __restrict__ agg,
                                                        const float* __restrict__ deg,
                                                        const float* __restrict__ Wself,
                                                        const float* __restrict__ Wneigh,
                                                        const float* __restrict__ b,
                                                        float* __restrict__ out, int N) {
    int tid = blockIdx.x * blockDim.x + threadIdx.x;
    if (tid >= N * 32) return;
    int n = tid >> 5, c = tid & 31;
    float inv = 1.0f / fmaxf(deg[n], 1.0f);
    const float* hrow = h1 + (size_t)n * NF;
    const float* arow = agg + (size_t)n * NF;
    float acc = b[c];
    #pragma unroll
    for (int k = 0; k < NF; ++k) {
        acc += hrow[k] * Wself[k * 32 + c];
        acc += (arow[k] * inv) * Wneigh[k * 32 + c];
    }
    out[tid] = acc;
}

// ---------------- launch ----------------

extern "C" void kernel_launch(void* const* d_in, const int* in_sizes, int n_in,
                              void* d_out, int out_size, void* d_ws, size_t ws_size,
                              hipStream_t stream) {
    const float* x        = (const float*)d_in[0];
    const int*   src      = (const int*)d_in[1];
    const int*   dst      = (const int*)d_in[2];
    const float* W_self1  = (const float*)d_in[3];
    const float* W_neigh1 = (const float*)d_in[4];
    const float* b1       = (const float*)d_in[5];
    const float* W_self2  = (const float*)d_in[6];
    const float* W_neigh2 = (const float*)d_in[7];
    const float* b2       = (const float*)d_in[8];
    float* out = (float*)d_out;

    const int N = in_sizes[0] / NF;          // 100000
    const int E = in_sizes[1];               // 1250000
    const int nbuckets = (N + BW - 1) / BW;  // 391

    // ws layout; gather tables 128B-aligned (round-10 proven: unaligned t1n
    // rows straddle 2 cachelines -> +70% FETCH)
    const size_t rsPad = ((size_t)N + 8) & ~7ull;
    int* gcursor   = (int*)d_ws;                      // [MAXB]
    unsigned short* w2p = (unsigned short*)(gcursor + MAXB);  // [8192] dense2 pack (16 KB)
    unsigned short* w1p = w2p + 8192;                 // [16384] dense1 pack (32 KB)
    int* row_start = (int*)(w1p + 16384);             // [N+1] padded
    int* csr_src   = row_start + rsPad;               // [E]
    uintptr_t pa = (uintptr_t)(csr_src + (((size_t)E + 7) & ~7ull));
    pa = (pa + 127) & ~(uintptr_t)127;                // 128B align
    float* bufA = (float*)pa;                         // [N][64] f32 (xs)
    unsigned* bucket = (unsigned*)bufA;               // [nbuckets][CAPMAX], dead before dense1
    unsigned short* t1n = (unsigned short*)(bufA + (size_t)N * NF);  // [N][64] bf16, 128B rows
    unsigned short* t2n = t1n + (size_t)N * NF;                      // [N][32] bf16, 64B rows
    size_t need = (size_t)((char*)(t2n + (size_t)N * 32) - (char*)d_ws);  // ~50.3 MB

    bool fast = ws_size >= need
             && E > 0
             && nbuckets <= MAXB
             && (size_t)nbuckets * CAPMAX <= (size_t)N * NF      // bucket fits in bufA alias
             && (size_t)E * 2 / (size_t)nbuckets <= CAPMAX       // 2x headroom over mean
             && N < (1 << 24)                                    // src fits in 24 bits
             && out_size >= N * 32;

    if (fast) {
        prep_kernel<<<5, 256, 0, stream>>>(gcursor, W_self1, W_neigh1,
                                           W_self2, W_neigh2, w1p, w2p);
        int dblocks  = (N + 127) / 128;                          // dense1 blocks
        int p1blocks = (E + P1_CHUNK - 1) / P1_CHUNK;            // p1 blocks
        // bucket must not alias bufA when p1 and dense1 share a launch:
        // disjoint bucket2 after t2n (checked via need2).
        unsigned* bucket2 = (unsigned*)(t2n + (((size_t)N * 32 + 63) & ~63ull));
        size_t need2 = (size_t)((char*)(bucket2 + (size_t)nbuckets * CAPMAX) - (char*)d_ws);
        if (ws_size >= need2) {
            p1_dense1_kernel<<<dblocks + p1blocks, 256, 0, stream>>>(
                src, dst, gcursor, bucket2, E, nbuckets, dblocks,
                x, w1p, b1, bufA, t1n, N);
            p2_csr_kernel<<<nbuckets, 256, 0, stream>>>(bucket2, gcursor,
                                                        row_start, csr_src, N, nbuckets);
        } else {
            // not enough ws for disjoint bucket: serialize (round-12 order)
            p1_dense1_kernel<<<p1blocks, 256, 0, stream>>>(     // p1 only
                src, dst, gcursor, bucket, E, nbuckets, 0,
                x, w1p, b1, bufA, t1n, N);
            p2_csr_kernel<<<nbuckets, 256, 0, stream>>>(bucket, gcursor,
                                                        row_start, csr_src, N, nbuckets);
            p1_dense1_kernel<<<dblocks, 256, 0, stream>>>(      // dense1 only
                src, dst, gcursor, bucket, E, nbuckets, dblocks,
                x, w1p, b1, bufA, t1n, N);
        }
        agg64_d2_kernel<<<(N + 15) / 16, 256, 0, stream>>>(
            t1n, bufA, row_start, csr_src, w2p, b2, out, t2n, N, E);
        agg32_kernel<<<(N + 15) / 16, 256, 0, stream>>>(out, t2n,
                                                        row_start, csr_src, N, E);
    } else {
        // fallback: atomic path (~51.6 MB)
        float* deg = (float*)d_ws;
        float* agg = deg + N;
        float* h1  = agg + (size_t)N * NF;
        hipMemsetAsync(deg, 0, (size_t)(N + (size_t)N * NF) * sizeof(float), stream);
        deg_kernel<<<(E + 255) / 256, 256, 0, stream>>>(dst, deg, E);
        int at = E * NF;
        agg_atomic_kernel<<<(at + 255) / 256, 256, 0, stream>>>(x, src, dst, agg, E);
        layer1_fb_kernel<<<(N * NF + 255) / 256, 256, 0, stream>>>(x, agg, deg, W_self1,
                                                                   W_neigh1, b1, h1, N);
        hipMemsetAsync(agg, 0, (size_t)N * NF * sizeof(float), stream);
        agg_atomic_kernel<<<(at + 255) / 256, 256, 0, stream>>>(h1, src, dst, agg, E);
        layer2_fb_kernel<<<(N * 32 + 255) / 256, 256, 0, stream>>>(h1, agg, deg, W_self2,
                                                                   W_neigh2, b2, out, N);
    }
}